// Round 1
// baseline (141.948 us; speedup 1.0000x reference)
//
#include <hip/hip_runtime.h>
#include <hip/hip_bf16.h>
#include <math.h>

using bf16 = __hip_bfloat16;
typedef __attribute__((ext_vector_type(8))) short short8;
typedef __attribute__((ext_vector_type(4))) short short4_;
typedef __attribute__((ext_vector_type(4))) float floatx4;

#define C_DIM   512
#define N_TOK   1024
#define NHEAD   8
#define HDIM    64
#define LN_EPSF 1e-5f

// RNE float -> bf16 bits
__device__ __forceinline__ unsigned short f2b(float f) {
    union { float f; unsigned int u; } v; v.f = f;
    unsigned int r = v.u + 0x7FFFu + ((v.u >> 16) & 1u);
    return (unsigned short)(r >> 16);
}
__device__ __forceinline__ float b2f(unsigned short u) {
    union { unsigned int i; float f; } v; v.i = ((unsigned int)u) << 16; return v.f;
}

// ---------------- Kernel 1: prep = LN stats | sincos table | w->frag-order bf16 -------
__global__ __launch_bounds__(256) void prep_kernel(
        const float* __restrict__ x, const float* __restrict__ w,
        float* __restrict__ mu, float* __restrict__ rsig,
        float* __restrict__ sc, unsigned short* __restrict__ wf) {
    __shared__ float red_s[4][64];
    __shared__ float red_q[4][64];
    const int bx = blockIdx.x;
    const int t  = threadIdx.x;
    if (bx < 128) {
        const int rl = t & 63;
        const int cg = t >> 6;
        const int r0 = bx * 64;
        const int b  = r0 >> 10;
        const int n  = (r0 & 1023) + rl;
        const float* xp = x + (size_t)b * C_DIM * N_TOK + n;
        float s = 0.f, q = 0.f;
        #pragma unroll 4
        for (int i = 0; i < 128; ++i) {
            float v = xp[(size_t)(cg * 128 + i) * N_TOK];
            s += v; q += v * v;
        }
        red_s[cg][rl] = s; red_q[cg][rl] = q;
        __syncthreads();
        if (cg == 0) {
            float S = red_s[0][rl] + red_s[1][rl] + red_s[2][rl] + red_s[3][rl];
            float Q = red_q[0][rl] + red_q[1][rl] + red_q[2][rl] + red_q[3][rl];
            float m   = S * (1.0f / C_DIM);
            float var = Q * (1.0f / C_DIM) - m * m;
            mu[r0 + rl]   = m;
            rsig[r0 + rl] = rsqrtf(var + LN_EPSF);
        }
    } else if (bx < 256) {
        const int idx = (bx - 128) * 256 + t;      // n*32 + f
        const int n = idx >> 5, f = idx & 31;
        const float fr = __expf((float)f * (-9.210340371976184f / 32.0f));
        float sv, cv;
        sincosf((float)n * fr, &sv, &cv);
        ((float2*)sc)[idx] = make_float2(sv, cv);
    } else {
        const int id   = (bx - 256) * 256 + t;     // chunk id in [0, 96*16*64)
        const int lane = id & 63;
        const int ksl  = (id >> 6) & 15;
        const int j16  = id >> 10;
        const int c    = lane & 15;
        const int quad = lane >> 4;
        const float* wp = w + (size_t)(j16 * 16 + c) * C_DIM + ksl * 32 + quad * 8;
        const float4 w0 = *(const float4*)(wp);
        const float4 w1 = *(const float4*)(wp + 4);
        short8 pk;
        pk[0] = (short)f2b(w0.x); pk[1] = (short)f2b(w0.y);
        pk[2] = (short)f2b(w0.z); pk[3] = (short)f2b(w0.w);
        pk[4] = (short)f2b(w1.x); pk[5] = (short)f2b(w1.y);
        pk[6] = (short)f2b(w1.z); pk[7] = (short)f2b(w1.w);
        *(short8*)(wf + (size_t)id * 8) = pk;
    }
}

// ---------------- Kernel 2: normalize + transpose -> A-fragment order ----------------
__global__ __launch_bounds__(256) void xnt_kernel(
        const float* __restrict__ x, const float* __restrict__ gamma,
        const float* __restrict__ beta, const float* __restrict__ mu,
        const float* __restrict__ rsig, unsigned short* __restrict__ xnf) {
    __shared__ short Sx[64][72];
    const int t  = threadIdx.x;
    const int c0 = blockIdx.x * 64;
    const int n0 = blockIdx.y * 64;
    const int b  = blockIdx.z;

    const int nq  = t & 15;
    const int crl = t >> 4;
    const int tok = b * N_TOK + n0 + nq * 4;
    const float4 m4 = *(const float4*)(mu + tok);
    const float4 r4 = *(const float4*)(rsig + tok);
    #pragma unroll
    for (int p = 0; p < 4; ++p) {
        const int c = c0 + p * 16 + crl;
        const float g = gamma[c], bt = beta[c];
        const float4 xv = *(const float4*)(x + (size_t)b * C_DIM * N_TOK + (size_t)c * N_TOK + n0 + nq * 4);
        Sx[nq * 4 + 0][p * 16 + crl] = (short)f2b((xv.x - m4.x) * r4.x * g + bt);
        Sx[nq * 4 + 1][p * 16 + crl] = (short)f2b((xv.y - m4.y) * r4.y * g + bt);
        Sx[nq * 4 + 2][p * 16 + crl] = (short)f2b((xv.z - m4.z) * r4.z * g + bt);
        Sx[nq * 4 + 3][p * 16 + crl] = (short)f2b((xv.w - m4.w) * r4.w * g + bt);
    }
    __syncthreads();
    const int wv   = t >> 6;
    const int lane = t & 63;
    const int cfr  = lane & 15;
    const int quad = lane >> 4;
    const int g16  = b * 64 + ((n0 >> 4) + wv);
    #pragma unroll
    for (int ks = 0; ks < 2; ++ks) {
        short8 v = *(const short8*)&Sx[wv * 16 + cfr][ks * 32 + quad * 8];
        *(short8*)(xnf + (((size_t)g16 * 16 + (c0 >> 5) + ks) * 64 + lane) * 8) = v;
    }
}

// ---------------- Kernel 3: QKV MFMA GEMM + bias + RoPE + fragment-order scatter -------
__global__ __launch_bounds__(256) void qkv_mfma_kernel(
        const unsigned short* __restrict__ xnf, const unsigned short* __restrict__ wf,
        const float* __restrict__ bias, const float* __restrict__ sc,
        unsigned short* __restrict__ qfr, unsigned short* __restrict__ kfr,
        unsigned short* __restrict__ vfr) {
    __shared__ short Es[4][64][72];

    const int t    = threadIdx.x;
    const int wv   = t >> 6;
    const int lane = t & 63;
    const int cl   = lane & 15;
    const int quad = lane >> 4;
    const int t0   = blockIdx.x * 128 + (wv & 1) * 64;
    const int j0w  = blockIdx.y * 128 + (wv >> 1) * 64;
    const int which = j0w >> 9;                 // 0=q 1=k 2=v
    const int h     = (j0w >> 6) & 7;
    const int b     = t0 >> 10;
    const int n0q   = t0 & 1023;
    const int bh    = b * NHEAD + h;

    const unsigned short* ap = xnf + (size_t)(t0 >> 4) * 8192 + lane * 8;
    const unsigned short* bp = wf  + (size_t)(j0w >> 4) * 8192 + lane * 8;

    floatx4 acc[4][4];
    #pragma unroll
    for (int i = 0; i < 4; ++i)
        #pragma unroll
        for (int j = 0; j < 4; ++j) acc[i][j] = (floatx4){0.f, 0.f, 0.f, 0.f};

    #pragma unroll 2
    for (int kt = 0; kt < 16; ++kt) {
        short8 af[4], bfr[4];
        #pragma unroll
        for (int tt = 0; tt < 4; ++tt) af[tt]  = *(const short8*)(ap + ((size_t)tt * 16 + kt) * 512);
        #pragma unroll
        for (int jt = 0; jt < 4; ++jt) bfr[jt] = *(const short8*)(bp + ((size_t)jt * 16 + kt) * 512);
        #pragma unroll
        for (int tt = 0; tt < 4; ++tt)
            #pragma unroll
            for (int jt = 0; jt < 4; ++jt)
                acc[tt][jt] = __builtin_amdgcn_mfma_f32_16x16x32_bf16(af[tt], bfr[jt], acc[tt][jt], 0, 0, 0);
    }

    float bj[4];
    #pragma unroll
    for (int jt = 0; jt < 4; ++jt) bj[jt] = bias[j0w + jt * 16 + cl];
    #pragma unroll
    for (int tt = 0; tt < 4; ++tt)
        #pragma unroll
        for (int jt = 0; jt < 4; ++jt)
            #pragma unroll
            for (int r = 0; r < 4; ++r)
                Es[wv][tt * 16 + quad * 4 + r][jt * 16 + cl] = (short)f2b(acc[tt][jt][r] + bj[jt]);
    // same-wave LDS read-after-write: ordered by lgkmcnt (no barrier needed)

    if (which == 2) {
        unsigned short* vfb = vfr + ((size_t)bh * 16 + (n0q >> 6)) * 4096;
        #pragma unroll
        for (int dt = 0; dt < 4; ++dt) {
            #pragma unroll
            for (int ks = 0; ks < 2; ++ks) {
                short8 pk;
                #pragma unroll
                for (int j = 0; j < 8; ++j)
                    pk[j] = Es[wv][ks * 32 + quad * 8 + j][dt * 16 + cl];
                *(short8*)(vfb + (((size_t)dt * 2 + ks) * 64 + lane) * 8) = pk;
            }
        }
    } else {
        const float oscale = (which == 0) ? 0.125f : 1.0f;
        unsigned short* base = (which == 0)
            ? qfr + ((size_t)bh * 64 + (n0q >> 4)) * 1024
            : kfr + ((size_t)bh * 16 + (n0q >> 6)) * 4096;
        #pragma unroll
        for (int mt = 0; mt < 4; ++mt) {
            const int n = n0q + mt * 16 + cl;
            const float* scp = sc + ((size_t)n * 32 + quad * 4) * 2;
            #pragma unroll
            for (int ks = 0; ks < 2; ++ks) {
                const short8 v8 = *(const short8*)&Es[wv][mt * 16 + cl][ks * 32 + quad * 8];
                const short8 p8 = *(const short8*)&Es[wv][mt * 16 + cl][(ks ^ 1) * 32 + quad * 8];
                const float* sp = scp + ks * 32;               // f = ks*16 + quad*4
                const float4 s0 = *(const float4*)sp;
                const float4 s1 = *(const float4*)(sp + 4);
                const float sv[4] = {s0.x, s0.z, s1.x, s1.z};
                const float cv[4] = {s0.y, s0.w, s1.y, s1.w};
                const float sgn = ks ? 1.0f : -1.0f;           // d<32 <=> ks==0
                short8 pk;
                #pragma unroll
                for (int j = 0; j < 8; ++j) {
                    const int f = j >> 1;
                    const float val = b2f((unsigned short)v8[j]);
                    const float par = b2f((unsigned short)p8[j]);
                    pk[j] = (short)f2b((val * cv[f] + sgn * par * sv[f]) * oscale);
                }
                *(short8*)(base + (((size_t)mt * 2 + ks) * 64 + lane) * 8) = pk;
            }
        }
    }
}

// ------- Kernel 4: MFMA flash attention, barrier-free, K/V direct from L2 ------------
// 32 q-rows per wave (2 q16 tiles), 4 INDEPENDENT waves per block — no __syncthreads
// anywhere in the kt loop. K/V per bh = 256 KB and 8 bh land on one XCD via the
// swizzle -> 2 MB, fully L2-resident, so LDS staging was pure overhead (learn_hip
// m169 lesson) and the old barrier pair drained the prefetch vmcnt every kt.
// K/V fragments are register double-buffered one kt ahead (named bufs, no runtime
// indexing -> no scratch). P bounce stays per-wave LDS (same-wave RAW, lgkm-ordered).
__global__ __launch_bounds__(256, 2) void attn_mfma_kernel(
        const unsigned short* __restrict__ qfr, const unsigned short* __restrict__ kfr,
        const unsigned short* __restrict__ vfr, float* __restrict__ out) {
    __shared__ __align__(16) short Plds[4][2][16][72];   // per-wave, per-u P strip (18 KB)

    const int t    = threadIdx.x;
    const int wv   = t >> 6;
    const int lane = t & 63;
    const int c    = lane & 15;
    const int quad = lane >> 4;
    const int i    = blockIdx.x;                   // [0,512)
    const int bh   = (i & 7) * 8 + ((i >> 3) & 7); // XCD swizzle: 8 bh per XCD
    const int q32  = (i >> 6) * 4 + wv;            // wave's 32-q tile, [0,32)
    const int b    = bh >> 3, h = bh & 7;

    const unsigned short* qp   = qfr + ((size_t)bh * 64 + q32 * 2) * 1024 + lane * 8;
    const unsigned short* kraw = kfr + (size_t)bh * 65536 + lane * 8;
    const unsigned short* vraw = vfr + (size_t)bh * 65536 + lane * 8;

    short8 qf[2][2];
    qf[0][0] = *(const short8*)(qp);
    qf[0][1] = *(const short8*)(qp + 512);
    qf[1][0] = *(const short8*)(qp + 1024);
    qf[1][1] = *(const short8*)(qp + 1536);

    floatx4 o_acc[4][2];
    float l_acc[2] = {0.f, 0.f};
    #pragma unroll
    for (int dt = 0; dt < 4; ++dt) {
        o_acc[dt][0] = (floatx4){0.f, 0.f, 0.f, 0.f};
        o_acc[dt][1] = (floatx4){0.f, 0.f, 0.f, 0.f};
    }

    short8 kfA[4][2], vfA[4][2], kfB[4][2], vfB[4][2];

    auto loadf = [&](short8 (&kf)[4][2], short8 (&vf)[4][2], int kt) {
        const unsigned short* kc = kraw + (size_t)kt * 4096;
        const unsigned short* vc = vraw + (size_t)kt * 4096;
        #pragma unroll
        for (int mt = 0; mt < 4; ++mt)
            #pragma unroll
            for (int ks = 0; ks < 2; ++ks) {
                kf[mt][ks] = *(const short8*)(kc + (mt * 2 + ks) * 512);
                vf[mt][ks] = *(const short8*)(vc + (mt * 2 + ks) * 512);
            }
    };

    auto step = [&](short8 (&kf)[4][2], short8 (&vf)[4][2]) {
        // S^T: rows = keys (mt tile), cols = q (c); one 16x16 tile per (mt, u)
        floatx4 st[4][2];
        #pragma unroll
        for (int mt = 0; mt < 4; ++mt)
            #pragma unroll
            for (int u = 0; u < 2; ++u) {
                floatx4 z = (floatx4){0.f, 0.f, 0.f, 0.f};
                z = __builtin_amdgcn_mfma_f32_16x16x32_bf16(kf[mt][0], qf[u][0], z, 0, 0, 0);
                st[mt][u] = __builtin_amdgcn_mfma_f32_16x16x32_bf16(kf[mt][1], qf[u][1], z, 0, 0, 0);
            }

        // fixed-shift exp (P = exp(S-16), shift-invariant); pack to per-wave LDS strip
        #pragma unroll
        for (int u = 0; u < 2; ++u)
            #pragma unroll
            for (int mt = 0; mt < 4; ++mt) {
                const float e0 = __expf(st[mt][u][0] - 16.0f);
                const float e1 = __expf(st[mt][u][1] - 16.0f);
                const float e2 = __expf(st[mt][u][2] - 16.0f);
                const float e3 = __expf(st[mt][u][3] - 16.0f);
                l_acc[u] += (e0 + e1) + (e2 + e3);
                short4_ pk;
                pk.x = (short)f2b(e0); pk.y = (short)f2b(e1);
                pk.z = (short)f2b(e2); pk.w = (short)f2b(e3);
                *(short4_*)&Plds[wv][u][c][mt * 16 + quad * 4] = pk;
            }

        // PV: O^T += V^T . P^T  (P round-trip is same-wave, lgkmcnt-ordered)
        #pragma unroll
        for (int u = 0; u < 2; ++u) {
            const short8 pf0 = *(const short8*)&Plds[wv][u][c][quad * 8];
            const short8 pf1 = *(const short8*)&Plds[wv][u][c][32 + quad * 8];
            #pragma unroll
            for (int dt = 0; dt < 4; ++dt) {
                o_acc[dt][u] = __builtin_amdgcn_mfma_f32_16x16x32_bf16(vf[dt][0], pf0, o_acc[dt][u], 0, 0, 0);
                o_acc[dt][u] = __builtin_amdgcn_mfma_f32_16x16x32_bf16(vf[dt][1], pf1, o_acc[dt][u], 0, 0, 0);
            }
        }
    };

    loadf(kfA, vfA, 0);
    #pragma unroll 1
    for (int kt = 0; kt < 16; kt += 2) {
        loadf(kfB, vfB, kt + 1);          // in flight across step A (no barrier drain)
        step(kfA, vfA);
        if (kt + 2 < 16) loadf(kfA, vfA, kt + 2);
        step(kfB, vfB);
    }

    #pragma unroll
    for (int u = 0; u < 2; ++u) {
        float l = l_acc[u];
        l += __shfl_xor(l, 16);
        l += __shfl_xor(l, 32);
        const float inv = 1.0f / l;
        const int qcol = (q32 * 2 + u) * 16 + c;
        #pragma unroll
        for (int dt = 0; dt < 4; ++dt)
            #pragma unroll
            for (int r = 0; r < 4; ++r) {
                const int d = dt * 16 + quad * 4 + r;
                out[((size_t)b * C_DIM + h * HDIM + d) * N_TOK + qcol] = o_acc[dt][u][r] * inv;
            }
    }
}

extern "C" void kernel_launch(void* const* d_in, const int* in_sizes, int n_in,
                              void* d_out, int out_size, void* d_ws, size_t ws_size,
                              hipStream_t stream) {
    const float* x     = (const float*)d_in[0];
    const float* w     = (const float*)d_in[1];
    const float* bias  = (const float*)d_in[2];
    const float* gamma = (const float*)d_in[3];
    const float* beta  = (const float*)d_in[4];
    float* out = (float*)d_out;

    char* ws = (char*)d_ws;
    float* mu   = (float*)ws;                                   // 32 KB
    float* rsig = (float*)(ws + 32768);                         // 32 KB
    unsigned short* qfr = (unsigned short*)(ws + 65536);        // 8 MB
    unsigned short* kfr = (unsigned short*)(ws + 65536 + 8388608);
    unsigned short* vfr = (unsigned short*)(ws + 65536 + 16777216);
    unsigned short* xnf = (unsigned short*)(ws + 65536 + 25165824);  // 8 MB
    unsigned short* wf  = (unsigned short*)(ws + 65536 + 33554432);  // 1.5 MB
    float* sc           = (float*)(ws + 65536 + 35127296);           // 256 KB

    hipLaunchKernelGGL(prep_kernel, dim3(640), dim3(256), 0, stream, x, w, mu, rsig, sc, wf);
    hipLaunchKernelGGL(xnt_kernel, dim3(8, 16, 8), dim3(256), 0, stream,
                       x, gamma, beta, mu, rsig, xnf);
    hipLaunchKernelGGL(qkv_mfma_kernel, dim3(64, 12), dim3(256), 0, stream,
                       xnf, wf, bias, sc, qfr, kfr, vfr);
    hipLaunchKernelGGL(attn_mfma_kernel, dim3(512), dim3(256), 0, stream, qfr, kfr, vfr, out);
}

// Round 3
// 138.954 us; speedup vs baseline: 1.0215x; 1.0215x over previous
//
#include <hip/hip_runtime.h>
#include <hip/hip_bf16.h>
#include <math.h>

using bf16 = __hip_bfloat16;
typedef __attribute__((ext_vector_type(8))) short short8;
typedef __attribute__((ext_vector_type(4))) float floatx4;
typedef __attribute__((ext_vector_type(4))) unsigned int uint4_;
typedef __attribute__((ext_vector_type(2))) unsigned int uint2_;

#define C_DIM   512
#define N_TOK   1024
#define NHEAD   8
#define HDIM    64
#define LN_EPSF 1e-5f

// RNE float -> bf16 bits (bit-hack; kept where values aren't pair-adjacent)
__device__ __forceinline__ unsigned short f2b(float f) {
    union { float f; unsigned int u; } v; v.f = f;
    unsigned int r = v.u + 0x7FFFu + ((v.u >> 16) & 1u);
    return (unsigned short)(r >> 16);
}
__device__ __forceinline__ float b2f(unsigned short u) {
    union { unsigned int i; float f; } v; v.i = ((unsigned int)u) << 16; return v.f;
}
// 2 floats -> packed bf16 pair in one VALU op (RNE, identical rounding to f2b)
__device__ __forceinline__ unsigned int cvt_pk_bf16(float lo, float hi) {
    unsigned int r;
    asm("v_cvt_pk_bf16_f32 %0, %1, %2" : "=v"(r) : "v"(lo), "v"(hi));
    return r;
}
// 2^x via the hardware transcendental, compiler-known (schedules/hazards handled)
__device__ __forceinline__ float fast_exp2(float x) {
    return __builtin_amdgcn_exp2f(x);
}

// ---------------- Kernel 1: prep = LN stats | sincos table | w->frag-order bf16 -------
__global__ __launch_bounds__(256) void prep_kernel(
        const float* __restrict__ x, const float* __restrict__ w,
        float* __restrict__ mu, float* __restrict__ rsig,
        float* __restrict__ sc, unsigned short* __restrict__ wf) {
    __shared__ float red_s[4][64];
    __shared__ float red_q[4][64];
    const int bx = blockIdx.x;
    const int t  = threadIdx.x;
    if (bx < 128) {
        const int rl = t & 63;
        const int cg = t >> 6;
        const int r0 = bx * 64;
        const int b  = r0 >> 10;
        const int n  = (r0 & 1023) + rl;
        const float* xp = x + (size_t)b * C_DIM * N_TOK + n;
        float s = 0.f, q = 0.f;
        #pragma unroll 4
        for (int i = 0; i < 128; ++i) {
            float v = xp[(size_t)(cg * 128 + i) * N_TOK];
            s += v; q += v * v;
        }
        red_s[cg][rl] = s; red_q[cg][rl] = q;
        __syncthreads();
        if (cg == 0) {
            float S = red_s[0][rl] + red_s[1][rl] + red_s[2][rl] + red_s[3][rl];
            float Q = red_q[0][rl] + red_q[1][rl] + red_q[2][rl] + red_q[3][rl];
            float m   = S * (1.0f / C_DIM);
            float var = Q * (1.0f / C_DIM) - m * m;
            mu[r0 + rl]   = m;
            rsig[r0 + rl] = rsqrtf(var + LN_EPSF);
        }
    } else if (bx < 256) {
        const int idx = (bx - 128) * 256 + t;      // n*32 + f
        const int n = idx >> 5, f = idx & 31;
        const float fr = __expf((float)f * (-9.210340371976184f / 32.0f));
        float sv, cv;
        sincosf((float)n * fr, &sv, &cv);
        ((float2*)sc)[idx] = make_float2(sv, cv);
    } else {
        const int id   = (bx - 256) * 256 + t;     // chunk id in [0, 96*16*64)
        const int lane = id & 63;
        const int ksl  = (id >> 6) & 15;
        const int j16  = id >> 10;
        const int c    = lane & 15;
        const int quad = lane >> 4;
        const float* wp = w + (size_t)(j16 * 16 + c) * C_DIM + ksl * 32 + quad * 8;
        const float4 w0 = *(const float4*)(wp);
        const float4 w1 = *(const float4*)(wp + 4);
        uint4_ pk;
        pk.x = cvt_pk_bf16(w0.x, w0.y);
        pk.y = cvt_pk_bf16(w0.z, w0.w);
        pk.z = cvt_pk_bf16(w1.x, w1.y);
        pk.w = cvt_pk_bf16(w1.z, w1.w);
        *(uint4_*)(wf + (size_t)id * 8) = pk;
    }
}

// ---------------- Kernel 2: normalize + transpose -> A-fragment order ----------------
__global__ __launch_bounds__(256) void xnt_kernel(
        const float* __restrict__ x, const float* __restrict__ gamma,
        const float* __restrict__ beta, const float* __restrict__ mu,
        const float* __restrict__ rsig, unsigned short* __restrict__ xnf) {
    __shared__ short Sx[64][72];
    const int t  = threadIdx.x;
    const int c0 = blockIdx.x * 64;
    const int n0 = blockIdx.y * 64;
    const int b  = blockIdx.z;

    const int nq  = t & 15;
    const int crl = t >> 4;
    const int tok = b * N_TOK + n0 + nq * 4;
    const float4 m4 = *(const float4*)(mu + tok);
    const float4 r4 = *(const float4*)(rsig + tok);
    #pragma unroll
    for (int p = 0; p < 4; ++p) {
        const int c = c0 + p * 16 + crl;
        const float g = gamma[c], bt = beta[c];
        const float4 xv = *(const float4*)(x + (size_t)b * C_DIM * N_TOK + (size_t)c * N_TOK + n0 + nq * 4);
        Sx[nq * 4 + 0][p * 16 + crl] = (short)f2b((xv.x - m4.x) * r4.x * g + bt);
        Sx[nq * 4 + 1][p * 16 + crl] = (short)f2b((xv.y - m4.y) * r4.y * g + bt);
        Sx[nq * 4 + 2][p * 16 + crl] = (short)f2b((xv.z - m4.z) * r4.z * g + bt);
        Sx[nq * 4 + 3][p * 16 + crl] = (short)f2b((xv.w - m4.w) * r4.w * g + bt);
    }
    __syncthreads();
    const int wv   = t >> 6;
    const int lane = t & 63;
    const int cfr  = lane & 15;
    const int quad = lane >> 4;
    const int g16  = b * 64 + ((n0 >> 4) + wv);
    #pragma unroll
    for (int ks = 0; ks < 2; ++ks) {
        short8 v = *(const short8*)&Sx[wv * 16 + cfr][ks * 32 + quad * 8];
        *(short8*)(xnf + (((size_t)g16 * 16 + (c0 >> 5) + ks) * 64 + lane) * 8) = v;
    }
}

// ---------------- Kernel 3: QKV MFMA GEMM + bias + RoPE + fragment-order scatter -------
// q-scale 0.125 is an exact power of 2 -> folded into the bias fmaf (commutes with
// RNE rounding bit-exactly). RoPE output packs via v_cvt_pk_bf16_f32 (1 op / pair).
__global__ __launch_bounds__(256) void qkv_mfma_kernel(
        const unsigned short* __restrict__ xnf, const unsigned short* __restrict__ wf,
        const float* __restrict__ bias, const float* __restrict__ sc,
        unsigned short* __restrict__ qfr, unsigned short* __restrict__ kfr,
        unsigned short* __restrict__ vfr) {
    __shared__ short Es[4][64][72];

    const int t    = threadIdx.x;
    const int wv   = t >> 6;
    const int lane = t & 63;
    const int cl   = lane & 15;
    const int quad = lane >> 4;
    const int t0   = blockIdx.x * 128 + (wv & 1) * 64;
    const int j0w  = blockIdx.y * 128 + (wv >> 1) * 64;
    const int which = j0w >> 9;                 // 0=q 1=k 2=v
    const int h     = (j0w >> 6) & 7;
    const int b     = t0 >> 10;
    const int n0q   = t0 & 1023;
    const int bh    = b * NHEAD + h;

    const unsigned short* ap = xnf + (size_t)(t0 >> 4) * 8192 + lane * 8;
    const unsigned short* bp = wf  + (size_t)(j0w >> 4) * 8192 + lane * 8;

    floatx4 acc[4][4];
    #pragma unroll
    for (int i = 0; i < 4; ++i)
        #pragma unroll
        for (int j = 0; j < 4; ++j) acc[i][j] = (floatx4){0.f, 0.f, 0.f, 0.f};

    #pragma unroll 2
    for (int kt = 0; kt < 16; ++kt) {
        short8 af[4], bfr[4];
        #pragma unroll
        for (int tt = 0; tt < 4; ++tt) af[tt]  = *(const short8*)(ap + ((size_t)tt * 16 + kt) * 512);
        #pragma unroll
        for (int jt = 0; jt < 4; ++jt) bfr[jt] = *(const short8*)(bp + ((size_t)jt * 16 + kt) * 512);
        #pragma unroll
        for (int tt = 0; tt < 4; ++tt)
            #pragma unroll
            for (int jt = 0; jt < 4; ++jt)
                acc[tt][jt] = __builtin_amdgcn_mfma_f32_16x16x32_bf16(af[tt], bfr[jt], acc[tt][jt], 0, 0, 0);
    }

    // fold q-scale (exact 2^-3) into the bias fmaf: Es holds pre-scaled S for q-waves
    const float os = (which == 0) ? 0.125f : 1.0f;
    float bj[4];
    #pragma unroll
    for (int jt = 0; jt < 4; ++jt) bj[jt] = bias[j0w + jt * 16 + cl] * os;
    #pragma unroll
    for (int tt = 0; tt < 4; ++tt)
        #pragma unroll
        for (int jt = 0; jt < 4; ++jt)
            #pragma unroll
            for (int r = 0; r < 4; ++r)
                Es[wv][tt * 16 + quad * 4 + r][jt * 16 + cl] = (short)f2b(fmaf(acc[tt][jt][r], os, bj[jt]));
    // same-wave LDS read-after-write: ordered by lgkmcnt (no barrier needed)

    if (which == 2) {
        unsigned short* vfb = vfr + ((size_t)bh * 16 + (n0q >> 6)) * 4096;
        #pragma unroll
        for (int dt = 0; dt < 4; ++dt) {
            #pragma unroll
            for (int ks = 0; ks < 2; ++ks) {
                short8 pk;
                #pragma unroll
                for (int j = 0; j < 8; ++j)
                    pk[j] = Es[wv][ks * 32 + quad * 8 + j][dt * 16 + cl];
                *(short8*)(vfb + (((size_t)dt * 2 + ks) * 64 + lane) * 8) = pk;
            }
        }
    } else {
        unsigned short* base = (which == 0)
            ? qfr + ((size_t)bh * 64 + (n0q >> 4)) * 1024
            : kfr + ((size_t)bh * 16 + (n0q >> 6)) * 4096;
        #pragma unroll
        for (int mt = 0; mt < 4; ++mt) {
            const int n = n0q + mt * 16 + cl;
            const float* scp = sc + ((size_t)n * 32 + quad * 4) * 2;
            #pragma unroll
            for (int ks = 0; ks < 2; ++ks) {
                const short8 v8 = *(const short8*)&Es[wv][mt * 16 + cl][ks * 32 + quad * 8];
                const short8 p8 = *(const short8*)&Es[wv][mt * 16 + cl][(ks ^ 1) * 32 + quad * 8];
                const float* sp = scp + ks * 32;               // f = ks*16 + quad*4
                const float4 s0 = *(const float4*)sp;
                const float4 s1 = *(const float4*)(sp + 4);
                const float sv[4] = {s0.x, s0.z, s1.x, s1.z};
                const float cv[4] = {s0.y, s0.w, s1.y, s1.w};
                const float sgn = ks ? 1.0f : -1.0f;           // d<32 <=> ks==0
                uint4_ pk;
                unsigned int pw[4];
                #pragma unroll
                for (int f = 0; f < 4; ++f) {
                    const float svs = sgn * sv[f];
                    const float a0 = b2f((unsigned short)v8[2 * f]);
                    const float a1 = b2f((unsigned short)v8[2 * f + 1]);
                    const float p0 = b2f((unsigned short)p8[2 * f]);
                    const float p1 = b2f((unsigned short)p8[2 * f + 1]);
                    pw[f] = cvt_pk_bf16(fmaf(p0, svs, a0 * cv[f]),
                                        fmaf(p1, svs, a1 * cv[f]));
                }
                pk.x = pw[0]; pk.y = pw[1]; pk.z = pw[2]; pk.w = pw[3];
                *(uint4_*)(base + (((size_t)mt * 2 + ks) * 64 + lane) * 8) = pk;
            }
        }
    }
}

// ------- Kernel 4: MFMA flash attention, barrier-free, K/V direct from L2 ------------
// R0 structure kept (proven correct, neutral perf). This round attacks the shared
// VALU path: exp2-domain softmax (1 fma + 1 v_exp per value vs sub+mul+exp), P packed
// with v_cvt_pk_bf16_f32 (2 ops per 4 values), setprio(1) around MFMA clusters
// (T5, measured +4-7% on attn with desynchronized waves).
__global__ __launch_bounds__(256, 2) void attn_mfma_kernel(
        const unsigned short* __restrict__ qfr, const unsigned short* __restrict__ kfr,
        const unsigned short* __restrict__ vfr, float* __restrict__ out) {
    __shared__ __align__(16) short Plds[4][2][16][72];   // per-wave, per-u P strip (18 KB)

    const int t    = threadIdx.x;
    const int wv   = t >> 6;
    const int lane = t & 63;
    const int c    = lane & 15;
    const int quad = lane >> 4;
    const int i    = blockIdx.x;                   // [0,512)
    const int bh   = (i & 7) * 8 + ((i >> 3) & 7); // XCD swizzle: 8 bh per XCD
    const int q32  = (i >> 6) * 4 + wv;            // wave's 32-q tile, [0,32)
    const int b    = bh >> 3, h = bh & 7;

    const unsigned short* qp   = qfr + ((size_t)bh * 64 + q32 * 2) * 1024 + lane * 8;
    const unsigned short* kraw = kfr + (size_t)bh * 65536 + lane * 8;
    const unsigned short* vraw = vfr + (size_t)bh * 65536 + lane * 8;

    short8 qf[2][2];
    qf[0][0] = *(const short8*)(qp);
    qf[0][1] = *(const short8*)(qp + 512);
    qf[1][0] = *(const short8*)(qp + 1024);
    qf[1][1] = *(const short8*)(qp + 1536);

    floatx4 o_acc[4][2];
    float l_acc[2] = {0.f, 0.f};
    #pragma unroll
    for (int dt = 0; dt < 4; ++dt) {
        o_acc[dt][0] = (floatx4){0.f, 0.f, 0.f, 0.f};
        o_acc[dt][1] = (floatx4){0.f, 0.f, 0.f, 0.f};
    }

    const float LOG2E  = 1.4426950408889634f;
    const float ESHIFT = -23.083120654223414f;     // -16 * log2(e): exp(s-16)=2^(s*log2e+ESHIFT)

    short8 kfA[4][2], vfA[4][2], kfB[4][2], vfB[4][2];

    auto loadf = [&](short8 (&kf)[4][2], short8 (&vf)[4][2], int kt) {
        const unsigned short* kc = kraw + (size_t)kt * 4096;
        const unsigned short* vc = vraw + (size_t)kt * 4096;
        #pragma unroll
        for (int mt = 0; mt < 4; ++mt)
            #pragma unroll
            for (int ks = 0; ks < 2; ++ks) {
                kf[mt][ks] = *(const short8*)(kc + (mt * 2 + ks) * 512);
                vf[mt][ks] = *(const short8*)(vc + (mt * 2 + ks) * 512);
            }
    };

    auto step = [&](short8 (&kf)[4][2], short8 (&vf)[4][2]) {
        // S^T: rows = keys (mt tile), cols = q (c); one 16x16 tile per (mt, u)
        floatx4 st[4][2];
        __builtin_amdgcn_s_setprio(1);
        #pragma unroll
        for (int mt = 0; mt < 4; ++mt)
            #pragma unroll
            for (int u = 0; u < 2; ++u) {
                floatx4 z = (floatx4){0.f, 0.f, 0.f, 0.f};
                z = __builtin_amdgcn_mfma_f32_16x16x32_bf16(kf[mt][0], qf[u][0], z, 0, 0, 0);
                st[mt][u] = __builtin_amdgcn_mfma_f32_16x16x32_bf16(kf[mt][1], qf[u][1], z, 0, 0, 0);
            }
        __builtin_amdgcn_s_setprio(0);

        // fixed-shift softmax in exp2 domain; pack pairs with v_cvt_pk_bf16_f32
        #pragma unroll
        for (int u = 0; u < 2; ++u)
            #pragma unroll
            for (int mt = 0; mt < 4; ++mt) {
                const float e0 = fast_exp2(fmaf(st[mt][u][0], LOG2E, ESHIFT));
                const float e1 = fast_exp2(fmaf(st[mt][u][1], LOG2E, ESHIFT));
                const float e2 = fast_exp2(fmaf(st[mt][u][2], LOG2E, ESHIFT));
                const float e3 = fast_exp2(fmaf(st[mt][u][3], LOG2E, ESHIFT));
                l_acc[u] += (e0 + e1) + (e2 + e3);
                uint2_ pk;
                pk.x = cvt_pk_bf16(e0, e1);
                pk.y = cvt_pk_bf16(e2, e3);
                *(uint2_*)&Plds[wv][u][c][mt * 16 + quad * 4] = pk;
            }

        // PV: O^T += V^T . P^T  (P round-trip is same-wave, lgkmcnt-ordered)
        #pragma unroll
        for (int u = 0; u < 2; ++u) {
            const short8 pf0 = *(const short8*)&Plds[wv][u][c][quad * 8];
            const short8 pf1 = *(const short8*)&Plds[wv][u][c][32 + quad * 8];
            __builtin_amdgcn_s_setprio(1);
            #pragma unroll
            for (int dt = 0; dt < 4; ++dt) {
                o_acc[dt][u] = __builtin_amdgcn_mfma_f32_16x16x32_bf16(vf[dt][0], pf0, o_acc[dt][u], 0, 0, 0);
                o_acc[dt][u] = __builtin_amdgcn_mfma_f32_16x16x32_bf16(vf[dt][1], pf1, o_acc[dt][u], 0, 0, 0);
            }
            __builtin_amdgcn_s_setprio(0);
        }
    };

    loadf(kfA, vfA, 0);
    #pragma unroll 1
    for (int kt = 0; kt < 16; kt += 2) {
        loadf(kfB, vfB, kt + 1);          // in flight across step A (no barrier drain)
        step(kfA, vfA);
        if (kt + 2 < 16) loadf(kfA, vfA, kt + 2);
        step(kfB, vfB);
    }

    #pragma unroll
    for (int u = 0; u < 2; ++u) {
        float l = l_acc[u];
        l += __shfl_xor(l, 16);
        l += __shfl_xor(l, 32);
        const float inv = 1.0f / l;
        const int qcol = (q32 * 2 + u) * 16 + c;
        #pragma unroll
        for (int dt = 0; dt < 4; ++dt)
            #pragma unroll
            for (int r = 0; r < 4; ++r) {
                const int d = dt * 16 + quad * 4 + r;
                out[((size_t)b * C_DIM + h * HDIM + d) * N_TOK + qcol] = o_acc[dt][u][r] * inv;
            }
    }
}

extern "C" void kernel_launch(void* const* d_in, const int* in_sizes, int n_in,
                              void* d_out, int out_size, void* d_ws, size_t ws_size,
                              hipStream_t stream) {
    const float* x     = (const float*)d_in[0];
    const float* w     = (const float*)d_in[1];
    const float* bias  = (const float*)d_in[2];
    const float* gamma = (const float*)d_in[3];
    const float* beta  = (const float*)d_in[4];
    float* out = (float*)d_out;

    char* ws = (char*)d_ws;
    float* mu   = (float*)ws;                                   // 32 KB
    float* rsig = (float*)(ws + 32768);                         // 32 KB
    unsigned short* qfr = (unsigned short*)(ws + 65536);        // 8 MB
    unsigned short* kfr = (unsigned short*)(ws + 65536 + 8388608);
    unsigned short* vfr = (unsigned short*)(ws + 65536 + 16777216);
    unsigned short* xnf = (unsigned short*)(ws + 65536 + 25165824);  // 8 MB
    unsigned short* wf  = (unsigned short*)(ws + 65536 + 33554432);  // 1.5 MB
    float* sc           = (float*)(ws + 65536 + 35127296);           // 256 KB

    hipLaunchKernelGGL(prep_kernel, dim3(640), dim3(256), 0, stream, x, w, mu, rsig, sc, wf);
    hipLaunchKernelGGL(xnt_kernel, dim3(8, 16, 8), dim3(256), 0, stream,
                       x, gamma, beta, mu, rsig, xnf);
    hipLaunchKernelGGL(qkv_mfma_kernel, dim3(64, 12), dim3(256), 0, stream,
                       xnf, wf, bias, sc, qfr, kfr, vfr);
    hipLaunchKernelGGL(attn_mfma_kernel, dim3(512), dim3(256), 0, stream, qfr, kfr, vfr, out);
}

// Round 4
// 125.640 us; speedup vs baseline: 1.1298x; 1.1060x over previous
//
#include <hip/hip_runtime.h>
#include <hip/hip_bf16.h>
#include <math.h>

using bf16 = __hip_bfloat16;
typedef __attribute__((ext_vector_type(8))) short short8;
typedef __attribute__((ext_vector_type(4))) float floatx4;
typedef __attribute__((ext_vector_type(4))) unsigned int uint4_;
typedef __attribute__((ext_vector_type(2))) unsigned int uint2_;

#define C_DIM   512
#define N_TOK   1024
#define NHEAD   8
#define HDIM    64
#define LN_EPSF 1e-5f

// RNE float -> bf16 bits (bit-hack; kept where values aren't pair-adjacent)
__device__ __forceinline__ unsigned short f2b(float f) {
    union { float f; unsigned int u; } v; v.f = f;
    unsigned int r = v.u + 0x7FFFu + ((v.u >> 16) & 1u);
    return (unsigned short)(r >> 16);
}
__device__ __forceinline__ float b2f(unsigned short u) {
    union { unsigned int i; float f; } v; v.i = ((unsigned int)u) << 16; return v.f;
}
// 2 floats -> packed bf16 pair in one VALU op (RNE, identical rounding to f2b)
__device__ __forceinline__ unsigned int cvt_pk_bf16(float lo, float hi) {
    unsigned int r;
    asm("v_cvt_pk_bf16_f32 %0, %1, %2" : "=v"(r) : "v"(lo), "v"(hi));
    return r;
}
// 2^x via the hardware transcendental, compiler-known (schedules/hazards handled)
__device__ __forceinline__ float fast_exp2(float x) {
    return __builtin_amdgcn_exp2f(x);
}

// ------ Kernel 1: fused LN(stats+normalize)+frag-transpose | sincos | w-conv ---------
// blocks 0..255:  one 32-token x-strip each: global->LDS once, per-token stats
//                 in-block, normalize, write xnf in MFMA A-frag order. Replaces the
//                 old prep-LN branch (128 blocks, 1 wave/SIMD, latency-exposed) AND
//                 the xnt kernel (second full read of x).
// blocks 256..383: RoPE sincos table (unchanged math).
// blocks 384..767: w -> frag-order bf16 (unchanged math).
__global__ __launch_bounds__(256) void lnx_kernel(
        const float* __restrict__ x, const float* __restrict__ w,
        const float* __restrict__ gamma, const float* __restrict__ beta,
        float* __restrict__ sc, unsigned short* __restrict__ wf,
        unsigned short* __restrict__ xnf) {
    __shared__ float xs[C_DIM][36];      // 73.7 KB; pad 36: 16B-aligned rows, spread banks
    __shared__ float red_s[8][32];
    __shared__ float red_q[8][32];
    __shared__ float muL[32], rsL[32];

    const int bx = blockIdx.x;
    const int t  = threadIdx.x;

    if (bx < 256) {
        const int b  = bx >> 5;              // batch
        const int n0 = (bx & 31) * 32;       // token strip
        const float* xb = x + (size_t)b * C_DIM * N_TOK;

        // P1: x strip -> LDS (float4 global reads, b128 LDS writes)
        #pragma unroll
        for (int i = 0; i < 16; ++i) {
            const int flat = i * 256 + t;    // [0,4096)
            const int c  = flat >> 3;
            const int f4 = flat & 7;
            const float4 v = *(const float4*)(xb + (size_t)c * N_TOK + n0 + f4 * 4);
            *(float4*)&xs[c][f4 * 4] = v;
        }
        __syncthreads();

        // P2: per-token mean/var (8 channel-chunks x 32 tokens; conflict-free reads)
        const int tl = t & 31, cg = t >> 5;
        float s = 0.f, q = 0.f;
        #pragma unroll 8
        for (int i2 = 0; i2 < 64; ++i2) {
            const float v = xs[cg * 64 + i2][tl];
            s += v; q += v * v;
        }
        red_s[cg][tl] = s; red_q[cg][tl] = q;
        __syncthreads();
        if (t < 32) {
            float S = 0.f, Q = 0.f;
            #pragma unroll
            for (int g2 = 0; g2 < 8; ++g2) { S += red_s[g2][t]; Q += red_q[g2][t]; }
            const float m   = S * (1.0f / C_DIM);
            const float var = Q * (1.0f / C_DIM) - m * m;
            muL[t] = m; rsL[t] = rsqrtf(var + LN_EPSF);
        }
        __syncthreads();

        // P3: normalize + frag-order write (token=lane&15, ch=kt*32+quad*8+j)
        const int wv   = t >> 6;
        const int lane = t & 63;
        const int cfr  = lane & 15;
        const int quad = lane >> 4;
        #pragma unroll
        for (int gg = 0; gg < 2; ++gg) {
            const int tloc = gg * 16 + cfr;
            const float m = muL[tloc], r = rsL[tloc];
            const int g16 = b * 64 + (n0 >> 4) + gg;
            #pragma unroll
            for (int kk = 0; kk < 4; ++kk) {
                const int kt  = wv * 4 + kk;
                const int ch0 = kt * 32 + quad * 8;
                const float4 g0 = *(const float4*)(gamma + ch0);
                const float4 g1 = *(const float4*)(gamma + ch0 + 4);
                const float4 b0 = *(const float4*)(beta + ch0);
                const float4 b1 = *(const float4*)(beta + ch0 + 4);
                float vv[8];
                #pragma unroll
                for (int j = 0; j < 8; ++j) vv[j] = (xs[ch0 + j][tloc] - m) * r;
                uint4_ pk;
                pk.x = cvt_pk_bf16(vv[0] * g0.x + b0.x, vv[1] * g0.y + b0.y);
                pk.y = cvt_pk_bf16(vv[2] * g0.z + b0.z, vv[3] * g0.w + b0.w);
                pk.z = cvt_pk_bf16(vv[4] * g1.x + b1.x, vv[5] * g1.y + b1.y);
                pk.w = cvt_pk_bf16(vv[6] * g1.z + b1.z, vv[7] * g1.w + b1.w);
                *(uint4_*)(xnf + (((size_t)g16 * 16 + kt) * 64 + lane) * 8) = pk;
            }
        }
    } else if (bx < 384) {
        const int idx = (bx - 256) * 256 + t;      // n*32 + f
        const int n = idx >> 5, f = idx & 31;
        const float fr = __expf((float)f * (-9.210340371976184f / 32.0f));
        float sv, cv;
        sincosf((float)n * fr, &sv, &cv);
        ((float2*)sc)[idx] = make_float2(sv, cv);
    } else {
        const int id   = (bx - 384) * 256 + t;     // chunk id in [0, 96*16*64)
        const int lane = id & 63;
        const int ksl  = (id >> 6) & 15;
        const int j16  = id >> 10;
        const int c    = lane & 15;
        const int quad = lane >> 4;
        const float* wp = w + (size_t)(j16 * 16 + c) * C_DIM + ksl * 32 + quad * 8;
        const float4 w0 = *(const float4*)(wp);
        const float4 w1 = *(const float4*)(wp + 4);
        uint4_ pk;
        pk.x = cvt_pk_bf16(w0.x, w0.y);
        pk.y = cvt_pk_bf16(w0.z, w0.w);
        pk.z = cvt_pk_bf16(w1.x, w1.y);
        pk.w = cvt_pk_bf16(w1.z, w1.w);
        *(uint4_*)(wf + (size_t)id * 8) = pk;
    }
}

// ---------------- Kernel 2: QKV MFMA GEMM + bias + RoPE + fragment-order scatter -------
// q-scale 0.125 is an exact power of 2 -> folded into the bias fmaf (commutes with
// RNE rounding bit-exactly). RoPE output packs via v_cvt_pk_bf16_f32 (1 op / pair).
__global__ __launch_bounds__(256) void qkv_mfma_kernel(
        const unsigned short* __restrict__ xnf, const unsigned short* __restrict__ wf,
        const float* __restrict__ bias, const float* __restrict__ sc,
        unsigned short* __restrict__ qfr, unsigned short* __restrict__ kfr,
        unsigned short* __restrict__ vfr) {
    __shared__ short Es[4][64][72];

    const int t    = threadIdx.x;
    const int wv   = t >> 6;
    const int lane = t & 63;
    const int cl   = lane & 15;
    const int quad = lane >> 4;
    const int t0   = blockIdx.x * 128 + (wv & 1) * 64;
    const int j0w  = blockIdx.y * 128 + (wv >> 1) * 64;
    const int which = j0w >> 9;                 // 0=q 1=k 2=v
    const int h     = (j0w >> 6) & 7;
    const int b     = t0 >> 10;
    const int n0q   = t0 & 1023;
    const int bh    = b * NHEAD + h;

    const unsigned short* ap = xnf + (size_t)(t0 >> 4) * 8192 + lane * 8;
    const unsigned short* bp = wf  + (size_t)(j0w >> 4) * 8192 + lane * 8;

    floatx4 acc[4][4];
    #pragma unroll
    for (int i = 0; i < 4; ++i)
        #pragma unroll
        for (int j = 0; j < 4; ++j) acc[i][j] = (floatx4){0.f, 0.f, 0.f, 0.f};

    #pragma unroll 2
    for (int kt = 0; kt < 16; ++kt) {
        short8 af[4], bfr[4];
        #pragma unroll
        for (int tt = 0; tt < 4; ++tt) af[tt]  = *(const short8*)(ap + ((size_t)tt * 16 + kt) * 512);
        #pragma unroll
        for (int jt = 0; jt < 4; ++jt) bfr[jt] = *(const short8*)(bp + ((size_t)jt * 16 + kt) * 512);
        #pragma unroll
        for (int tt = 0; tt < 4; ++tt)
            #pragma unroll
            for (int jt = 0; jt < 4; ++jt)
                acc[tt][jt] = __builtin_amdgcn_mfma_f32_16x16x32_bf16(af[tt], bfr[jt], acc[tt][jt], 0, 0, 0);
    }

    // fold q-scale (exact 2^-3) into the bias fmaf: Es holds pre-scaled S for q-waves
    const float os = (which == 0) ? 0.125f : 1.0f;
    float bj[4];
    #pragma unroll
    for (int jt = 0; jt < 4; ++jt) bj[jt] = bias[j0w + jt * 16 + cl] * os;
    #pragma unroll
    for (int tt = 0; tt < 4; ++tt)
        #pragma unroll
        for (int jt = 0; jt < 4; ++jt)
            #pragma unroll
            for (int r = 0; r < 4; ++r)
                Es[wv][tt * 16 + quad * 4 + r][jt * 16 + cl] = (short)f2b(fmaf(acc[tt][jt][r], os, bj[jt]));
    // same-wave LDS read-after-write: ordered by lgkmcnt (no barrier needed)

    if (which == 2) {
        unsigned short* vfb = vfr + ((size_t)bh * 16 + (n0q >> 6)) * 4096;
        #pragma unroll
        for (int dt = 0; dt < 4; ++dt) {
            #pragma unroll
            for (int ks = 0; ks < 2; ++ks) {
                short8 pk;
                #pragma unroll
                for (int j = 0; j < 8; ++j)
                    pk[j] = Es[wv][ks * 32 + quad * 8 + j][dt * 16 + cl];
                *(short8*)(vfb + (((size_t)dt * 2 + ks) * 64 + lane) * 8) = pk;
            }
        }
    } else {
        unsigned short* base = (which == 0)
            ? qfr + ((size_t)bh * 64 + (n0q >> 4)) * 1024
            : kfr + ((size_t)bh * 16 + (n0q >> 6)) * 4096;
        #pragma unroll
        for (int mt = 0; mt < 4; ++mt) {
            const int n = n0q + mt * 16 + cl;
            const float* scp = sc + ((size_t)n * 32 + quad * 4) * 2;
            #pragma unroll
            for (int ks = 0; ks < 2; ++ks) {
                const short8 v8 = *(const short8*)&Es[wv][mt * 16 + cl][ks * 32 + quad * 8];
                const short8 p8 = *(const short8*)&Es[wv][mt * 16 + cl][(ks ^ 1) * 32 + quad * 8];
                const float* sp = scp + ks * 32;               // f = ks*16 + quad*4
                const float4 s0 = *(const float4*)sp;
                const float4 s1 = *(const float4*)(sp + 4);
                const float sv[4] = {s0.x, s0.z, s1.x, s1.z};
                const float cv[4] = {s0.y, s0.w, s1.y, s1.w};
                const float sgn = ks ? 1.0f : -1.0f;           // d<32 <=> ks==0
                uint4_ pk;
                unsigned int pw[4];
                #pragma unroll
                for (int f = 0; f < 4; ++f) {
                    const float svs = sgn * sv[f];
                    const float a0 = b2f((unsigned short)v8[2 * f]);
                    const float a1 = b2f((unsigned short)v8[2 * f + 1]);
                    const float p0 = b2f((unsigned short)p8[2 * f]);
                    const float p1 = b2f((unsigned short)p8[2 * f + 1]);
                    pw[f] = cvt_pk_bf16(fmaf(p0, svs, a0 * cv[f]),
                                        fmaf(p1, svs, a1 * cv[f]));
                }
                pk.x = pw[0]; pk.y = pw[1]; pk.z = pw[2]; pk.w = pw[3];
                *(uint4_*)(base + (((size_t)mt * 2 + ks) * 64 + lane) * 8) = pk;
            }
        }
    }
}

// ------- Kernel 3: MFMA flash attention, barrier-free, K/V direct from L2 ------------
// Unchanged from R3 (exp2-domain softmax, cvt_pk P-pack, setprio around MFMA).
__global__ __launch_bounds__(256, 2) void attn_mfma_kernel(
        const unsigned short* __restrict__ qfr, const unsigned short* __restrict__ kfr,
        const unsigned short* __restrict__ vfr, float* __restrict__ out) {
    __shared__ __align__(16) short Plds[4][2][16][72];   // per-wave, per-u P strip (18 KB)

    const int t    = threadIdx.x;
    const int wv   = t >> 6;
    const int lane = t & 63;
    const int c    = lane & 15;
    const int quad = lane >> 4;
    const int i    = blockIdx.x;                   // [0,512)
    const int bh   = (i & 7) * 8 + ((i >> 3) & 7); // XCD swizzle: 8 bh per XCD
    const int q32  = (i >> 6) * 4 + wv;            // wave's 32-q tile, [0,32)
    const int b    = bh >> 3, h = bh & 7;

    const unsigned short* qp   = qfr + ((size_t)bh * 64 + q32 * 2) * 1024 + lane * 8;
    const unsigned short* kraw = kfr + (size_t)bh * 65536 + lane * 8;
    const unsigned short* vraw = vfr + (size_t)bh * 65536 + lane * 8;

    short8 qf[2][2];
    qf[0][0] = *(const short8*)(qp);
    qf[0][1] = *(const short8*)(qp + 512);
    qf[1][0] = *(const short8*)(qp + 1024);
    qf[1][1] = *(const short8*)(qp + 1536);

    floatx4 o_acc[4][2];
    float l_acc[2] = {0.f, 0.f};
    #pragma unroll
    for (int dt = 0; dt < 4; ++dt) {
        o_acc[dt][0] = (floatx4){0.f, 0.f, 0.f, 0.f};
        o_acc[dt][1] = (floatx4){0.f, 0.f, 0.f, 0.f};
    }

    const float LOG2E  = 1.4426950408889634f;
    const float ESHIFT = -23.083120654223414f;     // -16 * log2(e): exp(s-16)=2^(s*log2e+ESHIFT)

    short8 kfA[4][2], vfA[4][2], kfB[4][2], vfB[4][2];

    auto loadf = [&](short8 (&kf)[4][2], short8 (&vf)[4][2], int kt) {
        const unsigned short* kc = kraw + (size_t)kt * 4096;
        const unsigned short* vc = vraw + (size_t)kt * 4096;
        #pragma unroll
        for (int mt = 0; mt < 4; ++mt)
            #pragma unroll
            for (int ks = 0; ks < 2; ++ks) {
                kf[mt][ks] = *(const short8*)(kc + (mt * 2 + ks) * 512);
                vf[mt][ks] = *(const short8*)(vc + (mt * 2 + ks) * 512);
            }
    };

    auto step = [&](short8 (&kf)[4][2], short8 (&vf)[4][2]) {
        // S^T: rows = keys (mt tile), cols = q (c); one 16x16 tile per (mt, u)
        floatx4 st[4][2];
        __builtin_amdgcn_s_setprio(1);
        #pragma unroll
        for (int mt = 0; mt < 4; ++mt)
            #pragma unroll
            for (int u = 0; u < 2; ++u) {
                floatx4 z = (floatx4){0.f, 0.f, 0.f, 0.f};
                z = __builtin_amdgcn_mfma_f32_16x16x32_bf16(kf[mt][0], qf[u][0], z, 0, 0, 0);
                st[mt][u] = __builtin_amdgcn_mfma_f32_16x16x32_bf16(kf[mt][1], qf[u][1], z, 0, 0, 0);
            }
        __builtin_amdgcn_s_setprio(0);

        // fixed-shift softmax in exp2 domain; pack pairs with v_cvt_pk_bf16_f32
        #pragma unroll
        for (int u = 0; u < 2; ++u)
            #pragma unroll
            for (int mt = 0; mt < 4; ++mt) {
                const float e0 = fast_exp2(fmaf(st[mt][u][0], LOG2E, ESHIFT));
                const float e1 = fast_exp2(fmaf(st[mt][u][1], LOG2E, ESHIFT));
                const float e2 = fast_exp2(fmaf(st[mt][u][2], LOG2E, ESHIFT));
                const float e3 = fast_exp2(fmaf(st[mt][u][3], LOG2E, ESHIFT));
                l_acc[u] += (e0 + e1) + (e2 + e3);
                uint2_ pk;
                pk.x = cvt_pk_bf16(e0, e1);
                pk.y = cvt_pk_bf16(e2, e3);
                *(uint2_*)&Plds[wv][u][c][mt * 16 + quad * 4] = pk;
            }

        // PV: O^T += V^T . P^T  (P round-trip is same-wave, lgkmcnt-ordered)
        #pragma unroll
        for (int u = 0; u < 2; ++u) {
            const short8 pf0 = *(const short8*)&Plds[wv][u][c][quad * 8];
            const short8 pf1 = *(const short8*)&Plds[wv][u][c][32 + quad * 8];
            __builtin_amdgcn_s_setprio(1);
            #pragma unroll
            for (int dt = 0; dt < 4; ++dt) {
                o_acc[dt][u] = __builtin_amdgcn_mfma_f32_16x16x32_bf16(vf[dt][0], pf0, o_acc[dt][u], 0, 0, 0);
                o_acc[dt][u] = __builtin_amdgcn_mfma_f32_16x16x32_bf16(vf[dt][1], pf1, o_acc[dt][u], 0, 0, 0);
            }
            __builtin_amdgcn_s_setprio(0);
        }
    };

    loadf(kfA, vfA, 0);
    #pragma unroll 1
    for (int kt = 0; kt < 16; kt += 2) {
        loadf(kfB, vfB, kt + 1);          // in flight across step A (no barrier drain)
        step(kfA, vfA);
        if (kt + 2 < 16) loadf(kfA, vfA, kt + 2);
        step(kfB, vfB);
    }

    #pragma unroll
    for (int u = 0; u < 2; ++u) {
        float l = l_acc[u];
        l += __shfl_xor(l, 16);
        l += __shfl_xor(l, 32);
        const float inv = 1.0f / l;
        const int qcol = (q32 * 2 + u) * 16 + c;
        #pragma unroll
        for (int dt = 0; dt < 4; ++dt)
            #pragma unroll
            for (int r = 0; r < 4; ++r) {
                const int d = dt * 16 + quad * 4 + r;
                out[((size_t)b * C_DIM + h * HDIM + d) * N_TOK + qcol] = o_acc[dt][u][r] * inv;
            }
    }
}

extern "C" void kernel_launch(void* const* d_in, const int* in_sizes, int n_in,
                              void* d_out, int out_size, void* d_ws, size_t ws_size,
                              hipStream_t stream) {
    const float* x     = (const float*)d_in[0];
    const float* w     = (const float*)d_in[1];
    const float* bias  = (const float*)d_in[2];
    const float* gamma = (const float*)d_in[3];
    const float* beta  = (const float*)d_in[4];
    float* out = (float*)d_out;

    char* ws = (char*)d_ws;
    unsigned short* qfr = (unsigned short*)(ws + 65536);        // 8 MB
    unsigned short* kfr = (unsigned short*)(ws + 65536 + 8388608);
    unsigned short* vfr = (unsigned short*)(ws + 65536 + 16777216);
    unsigned short* xnf = (unsigned short*)(ws + 65536 + 25165824);  // 8 MB
    unsigned short* wf  = (unsigned short*)(ws + 65536 + 33554432);  // 1.5 MB
    float* sc           = (float*)(ws + 65536 + 35127296);           // 256 KB

    hipLaunchKernelGGL(lnx_kernel, dim3(768), dim3(256), 0, stream,
                       x, w, gamma, beta, sc, wf, xnf);
    hipLaunchKernelGGL(qkv_mfma_kernel, dim3(64, 12), dim3(256), 0, stream,
                       xnf, wf, bias, sc, qfr, kfr, vfr);
    hipLaunchKernelGGL(attn_mfma_kernel, dim3(512), dim3(256), 0, stream, qfr, kfr, vfr, out);
}